// Round 5
// baseline (6794.129 us; speedup 1.0000x reference)
//
#include <hip/hip_runtime.h>
#include <hip/hip_bf16.h>

#define NN 100000
#define EE 3200000
#define KXD 256
#define HH 128
#define GG 128
#define DD 257

// ---- dtype-generic load helpers (bf=1: packed bf16, bf=0: f32) ----
__device__ inline float ldf(const void* p, size_t i, int bf) {
    if (bf) return __uint_as_float(((unsigned int)((const unsigned short*)p)[i]) << 16);
    return ((const float*)p)[i];
}
__device__ inline float4 ld4(const void* p, size_t i, int bf) {   // i % 4 == 0
    if (bf) {
        uint2 ab = *(const uint2*)((const unsigned short*)p + i);
        float4 r;
        r.x = __uint_as_float(ab.x << 16);
        r.y = __uint_as_float(ab.x & 0xffff0000u);
        r.z = __uint_as_float(ab.y << 16);
        r.w = __uint_as_float(ab.y & 0xffff0000u);
        return r;
    }
    return *(const float4*)((const float*)p + i);
}
__device__ inline float cvt(float v) { return v; }
__device__ inline float cvt(__hip_bfloat16 v) { return __bfloat162float(v); }

// ---- probe: edge int64-ness (flags[0]) and float bf16-ness (flags[1]) ----
__global__ void k_probe(const int* __restrict__ ei32, const unsigned int* __restrict__ Xw,
                        int* __restrict__ flags)
{
    __shared__ int s_edge_any, s_bf_hits;
    const int t = threadIdx.x;
    if (t == 0) { s_edge_any = 0; s_bf_hits = 0; }
    __syncthreads();
    int acc = 0;
    #pragma unroll
    for (int j = 0; j < 64; ++j) {
        int k = (t + 256 * j) * 195;                 // < EE
        acc |= ei32[2 * (size_t)k + 1];
    }
    if (acc) atomicOr(&s_edge_any, 1);
    unsigned int lo = Xw[t] & 0xffffu;
    int e = (int)((lo >> 7) & 0xff);
    if (lo == 0u || (e >= 100 && e <= 140)) atomicAdd(&s_bf_hits, 1);
    __syncthreads();
    if (t == 0) {
        flags[0] = (s_edge_any == 0) ? 1 : 0;   // 1 = int64 edges
        flags[1] = (s_bf_hits >= 192) ? 1 : 0;  // 1 = bf16 floats
    }
}

// ---- edge decode ----
__device__ inline void edge_sd(const int* ei, int e, int i64, int& s, int& d) {
    if (i64) { s = ei[2 * (size_t)e]; d = ei[2 * ((size_t)EE + e)]; }
    else     { s = ei[e];             d = ei[(size_t)EE + e]; }
    s = min(max(s, 0), NN - 1);
    d = min(max(d, 0), NN - 1);
}

// ---- degree + sum(T[src]) per dst ----
__global__ void k_norm(const int* __restrict__ ei, const int* __restrict__ flags,
                       const void* __restrict__ T,
                       float* __restrict__ cnt, float* __restrict__ sumT)
{
    int e = blockIdx.x * 256 + threadIdx.x;
    if (e >= EE) return;
    int s, d;
    edge_sd(ei, e, flags[0], s, d);
    unsafeAtomicAdd(&cnt[d], 1.0f);
    unsafeAtomicAdd(&sumT[d], ldf(T, s, flags[1]));
}

// ---- GEMM1: phi = relu(X @ Wphi + bphi).  LDS: 32+16 = 48 KB ----
__global__ __launch_bounds__(256) void k_phi(const void* __restrict__ X,
    const void* __restrict__ W, const void* __restrict__ b,
    const int* __restrict__ flags, float* __restrict__ phi)
{
    __shared__ float Wl[64 * HH];    // 32 KB chunk (64 k-rows)
    __shared__ float Xt[KXD][16];    // 16 KB
    const int bf = flags[1];
    const int t = threadIdx.x;
    const int row0 = blockIdx.x * 16;

    for (int i = t; i < 16 * (KXD / 4); i += 256) {
        int r = i & 15, kq = i >> 4;
        float4 v = ld4(X, (size_t)(row0 + r) * KXD + kq * 4, bf);
        Xt[kq * 4 + 0][r] = v.x; Xt[kq * 4 + 1][r] = v.y;
        Xt[kq * 4 + 2][r] = v.z; Xt[kq * 4 + 3][r] = v.w;
    }

    const int col2  = (t & 63) * 2;
    const int rbase = (t >> 6) * 4;
    float acc[4][2] = {};

    for (int ch = 0; ch < 4; ++ch) {
        __syncthreads();
        for (int i = t * 4; i < 64 * HH; i += 256 * 4)
            *(float4*)&Wl[i] = ld4(W, (size_t)ch * 64 * HH + i, bf);
        __syncthreads();
        #pragma unroll 4
        for (int k = 0; k < 64; ++k) {
            float2 w = *(const float2*)&Wl[k * HH + col2];
            float4 x = *(const float4*)&Xt[ch * 64 + k][rbase];
            acc[0][0] += x.x * w.x; acc[0][1] += x.x * w.y;
            acc[1][0] += x.y * w.x; acc[1][1] += x.y * w.y;
            acc[2][0] += x.z * w.x; acc[2][1] += x.z * w.y;
            acc[3][0] += x.w * w.x; acc[3][1] += x.w * w.y;
        }
    }
    float bx = ldf(b, col2, bf), by = ldf(b, col2 + 1, bf);
    #pragma unroll
    for (int r = 0; r < 4; ++r) {
        int row = row0 + rbase + r;
        float2 o;
        o.x = fmaxf(acc[r][0] + bx, 0.f);
        o.y = fmaxf(acc[r][1] + by, 0.f);
        *(float2*)&phi[(size_t)row * HH + col2] = o;
    }
}

// ---- GEMM2: h = (T .* phi) @ Wgcn.  LDS: 32+8 = 40 KB ----
__global__ __launch_bounds__(256) void k_gcn(const float* __restrict__ phi,
    const void* __restrict__ T, const void* __restrict__ W,
    const int* __restrict__ flags, float* __restrict__ h)
{
    __shared__ float Wl[64 * GG];
    __shared__ float Xt[HH][16];
    const int bf = flags[1];
    const int t = threadIdx.x;
    const int row0 = blockIdx.x * 16;

    for (int i = t; i < 16 * (HH / 4); i += 256) {
        int r = i & 15, kq = i >> 4;
        float tv = ldf(T, row0 + r, bf);
        float4 v = *(const float4*)&phi[(size_t)(row0 + r) * HH + kq * 4];
        Xt[kq * 4 + 0][r] = v.x * tv; Xt[kq * 4 + 1][r] = v.y * tv;
        Xt[kq * 4 + 2][r] = v.z * tv; Xt[kq * 4 + 3][r] = v.w * tv;
    }

    const int col2  = (t & 63) * 2;
    const int rbase = (t >> 6) * 4;
    float acc[4][2] = {};

    for (int ch = 0; ch < 2; ++ch) {
        __syncthreads();
        for (int i = t * 4; i < 64 * GG; i += 256 * 4)
            *(float4*)&Wl[i] = ld4(W, (size_t)ch * 64 * GG + i, bf);
        __syncthreads();
        #pragma unroll 4
        for (int k = 0; k < 64; ++k) {
            float2 w = *(const float2*)&Wl[k * GG + col2];
            float4 x = *(const float4*)&Xt[ch * 64 + k][rbase];
            acc[0][0] += x.x * w.x; acc[0][1] += x.x * w.y;
            acc[1][0] += x.y * w.x; acc[1][1] += x.y * w.y;
            acc[2][0] += x.z * w.x; acc[2][1] += x.z * w.y;
            acc[3][0] += x.w * w.x; acc[3][1] += x.w * w.y;
        }
    }
    #pragma unroll
    for (int r = 0; r < 4; ++r) {
        int row = row0 + rbase + r;
        float2 o; o.x = acc[r][0]; o.y = acc[r][1];
        *(float2*)&h[(size_t)row * GG + col2] = o;
    }
}

// ---- per-node: dis, 1/deg, z ----
__global__ void k_prep(const float* __restrict__ cnt, const float* __restrict__ sumT,
                       float* __restrict__ dis, float* __restrict__ inv,
                       float* __restrict__ z)
{
    int i = blockIdx.x * 256 + threadIdx.x;
    if (i < NN) {
        float c = cnt[i];
        dis[i] = rsqrtf(c + 1.f);
        inv[i] = 1.f / (c + 1.f);
        z[i]   = sumT[i] / fmaxf(c, 1.f);
    }
}

// ---- edge scatter: agg[dst] += h[src] * coef ----
__global__ __launch_bounds__(256) void k_scatter(const int* __restrict__ ei,
    const int* __restrict__ flags, const float* __restrict__ dis,
    const float* __restrict__ h, float* __restrict__ agg)
{
    long long idx = (long long)blockIdx.x * 256 + threadIdx.x;
    int e = (int)(idx >> 5);
    int q = ((int)idx & 31) * 4;
    int s, d;
    edge_sd(ei, e, flags[0], s, d);
    float coef = dis[s] * dis[d];
    float4 v = *(const float4*)&h[(size_t)s * GG + q];
    float* ap = &agg[(size_t)d * GG + q];
    unsafeAtomicAdd(ap + 0, v.x * coef);
    unsafeAtomicAdd(ap + 1, v.y * coef);
    unsafeAtomicAdd(ap + 2, v.z * coef);
    unsafeAtomicAdd(ap + 3, v.w * coef);
}

// ---- finalize: rep_gnn (in-place on agg) + f32 rep_post out ----
__global__ void k_fin(const float* __restrict__ phi, const float* __restrict__ h,
                      float* __restrict__ agg, const float* __restrict__ inv,
                      const float* __restrict__ z, const void* __restrict__ bg,
                      const int* __restrict__ flags, float* __restrict__ out_rep)
{
    int idx = blockIdx.x * 256 + threadIdx.x;
    if (idx >= NN * DD) return;
    int i = idx / DD;
    int c = idx - i * DD;
    float v;
    if (c < HH) {
        v = phi[(size_t)i * HH + c];
    } else if (c < HH + GG) {
        int g = c - HH;
        float val = agg[(size_t)i * GG + g] + h[(size_t)i * GG + g] * inv[i]
                  + ldf(bg, g, flags[1]);
        v = fmaxf(val, 0.f);
        agg[(size_t)i * GG + g] = v;
    } else {
        v = z[i];
    }
    out_rep[idx] = v;      // f32 output
}

// ---- fused heads, templated on weight element type; f32 output ----
template <typename ET>
__device__ void heads_body(const ET* __restrict__ W00, const ET* __restrict__ b00,
    const ET* __restrict__ W10, const ET* __restrict__ b10,
    const ET* __restrict__ W01, const ET* __restrict__ b01,
    const ET* __restrict__ W11, const ET* __restrict__ b11,
    float* __restrict__ out, float (*rp)[16], float (*wred)[16],
    float* e256, int row0, int t)
{
    const int lane = t & 63, wid = t >> 6;
    #pragma unroll 1
    for (int head = 0; head < 2; ++head) {
        const ET* WH = head ? W10 : W00;
        const ET* bH = head ? b10 : b00;
        const ET* WV = head ? W11 : W01;
        const float bV = cvt(head ? b11[0] : b01[0]);

        float bcol = cvt(bH[t]);
        float acc[16];
        #pragma unroll
        for (int r = 0; r < 16; ++r) acc[r] = bcol;

        #pragma unroll 4
        for (int k = 0; k < DD; ++k) {
            float w = cvt(WH[(size_t)k * DD + t]);
            float4 x0 = *(const float4*)&rp[k][0];
            float4 x1 = *(const float4*)&rp[k][4];
            float4 x2 = *(const float4*)&rp[k][8];
            float4 x3 = *(const float4*)&rp[k][12];
            acc[0]  += x0.x * w; acc[1]  += x0.y * w; acc[2]  += x0.z * w; acc[3]  += x0.w * w;
            acc[4]  += x1.x * w; acc[5]  += x1.y * w; acc[6]  += x1.z * w; acc[7]  += x1.w * w;
            acc[8]  += x2.x * w; acc[9]  += x2.y * w; acc[10] += x2.z * w; acc[11] += x2.w * w;
            acc[12] += x3.x * w; acc[13] += x3.y * w; acc[14] += x3.z * w; acc[15] += x3.w * w;
        }

        if (t < 16) {   // column 256
            float a = cvt(bH[256]);
            for (int k = 0; k < DD; ++k) a += rp[k][t] * cvt(WH[(size_t)k * DD + 256]);
            e256[t] = fmaxf(a, 0.f) * cvt(WV[256]);
        }

        float wv = cvt(WV[t]);
        #pragma unroll
        for (int r = 0; r < 16; ++r) {
            float v = fmaxf(acc[r], 0.f) * wv;
            #pragma unroll
            for (int off = 32; off > 0; off >>= 1) v += __shfl_down(v, off);
            if (lane == 0) wred[wid][r] = v;
        }
        __syncthreads();
        if (t < 16) {
            float y = wred[0][t] + wred[1][t] + wred[2][t] + wred[3][t] + e256[t] + bV;
            out[(size_t)head * NN + row0 + t] = y;    // f32 output
        }
        __syncthreads();
    }
}

__global__ __launch_bounds__(256) void k_heads(const float* __restrict__ phi,
    const float* __restrict__ repg, const float* __restrict__ z,
    const void* W00, const void* b00, const void* W10, const void* b10,
    const void* W01, const void* b01, const void* W11, const void* b11,
    const int* __restrict__ flags, float* __restrict__ out)
{
    __shared__ float rp[DD][16];
    __shared__ float wred[4][16];
    __shared__ float e256[16];
    const int t = threadIdx.x;
    const int row0 = blockIdx.x * 16;

    for (int i = t; i < 16 * DD; i += 256) {
        int r = i / DD, k = i - r * DD;
        float v;
        if (k < HH)            v = phi[(size_t)(row0 + r) * HH + k];
        else if (k < HH + GG)  v = repg[(size_t)(row0 + r) * GG + (k - HH)];
        else                   v = z[row0 + r];
        rp[k][r] = v;
    }
    __syncthreads();

    if (flags[1])
        heads_body<__hip_bfloat16>((const __hip_bfloat16*)W00, (const __hip_bfloat16*)b00,
            (const __hip_bfloat16*)W10, (const __hip_bfloat16*)b10,
            (const __hip_bfloat16*)W01, (const __hip_bfloat16*)b01,
            (const __hip_bfloat16*)W11, (const __hip_bfloat16*)b11,
            out, rp, wred, e256, row0, t);
    else
        heads_body<float>((const float*)W00, (const float*)b00,
            (const float*)W10, (const float*)b10,
            (const float*)W01, (const float*)b01,
            (const float*)W11, (const float*)b11,
            out, rp, wred, e256, row0, t);
}

extern "C" void kernel_launch(void* const* d_in, const int* in_sizes, int n_in,
                              void* d_out, int out_size, void* d_ws, size_t ws_size,
                              hipStream_t stream)
{
    const void* X    = d_in[0];
    const void* T    = d_in[1];
    const int*  ei   = (const int*)d_in[2];
    const void* Wphi = d_in[3];
    const void* bphi = d_in[4];
    const void* Wgcn = d_in[5];
    const void* bgcn = d_in[6];
    const void* W00  = d_in[7];
    const void* b00  = d_in[8];
    const void* W10  = d_in[9];
    const void* b10  = d_in[10];
    const void* W01  = d_in[11];
    const void* b01  = d_in[12];
    const void* W11  = d_in[13];
    const void* b11  = d_in[14];
    float* out = (float*)d_out;      // reference output dtype is float32

    float* ws   = (float*)d_ws;
    float* phi  = ws;                          // N*H f32
    float* h    = phi + (size_t)NN * HH;       // N*G f32
    float* agg  = h   + (size_t)NN * GG;       // N*G f32 (-> rep_gnn in place)
    float* cnt  = agg + (size_t)NN * GG;       // N
    float* sumT = cnt + NN;                    // N
    float* dis  = sumT + NN;                   // N
    float* inv  = dis + NN;                    // N
    float* z    = inv + NN;                    // N
    int*   flags= (int*)(z + NN);              // 2

    hipMemsetAsync(agg, 0, ((size_t)NN * GG + 2 * (size_t)NN) * sizeof(float), stream);

    k_probe  <<<1,                     256, 0, stream>>>(ei, (const unsigned int*)X, flags);
    k_norm   <<<(EE + 255) / 256,      256, 0, stream>>>(ei, flags, T, cnt, sumT);
    k_phi    <<<NN / 16,               256, 0, stream>>>(X, Wphi, bphi, flags, phi);
    k_gcn    <<<NN / 16,               256, 0, stream>>>(phi, T, Wgcn, flags, h);
    k_prep   <<<(NN + 255) / 256,      256, 0, stream>>>(cnt, sumT, dis, inv, z);
    k_scatter<<<EE / 8,                256, 0, stream>>>(ei, flags, dis, h, agg);
    k_fin    <<<(NN * DD + 255) / 256, 256, 0, stream>>>(phi, h, agg, inv, z, bgcn,
                                                         flags, out + 2 * (size_t)NN);
    k_heads  <<<NN / 16,               256, 0, stream>>>(phi, agg, z, W00, b00, W10, b10,
                                                         W01, b01, W11, b11, flags, out);
}

// Round 6
// 1757.496 us; speedup vs baseline: 3.8658x; 3.8658x over previous
//
#include <hip/hip_runtime.h>
#include <hip/hip_bf16.h>

#define NN 100000
#define EE 3200000
#define KXD 256
#define HH 128
#define GG 128
#define DD 257

// ---- dtype-generic load helpers (bf=1: packed bf16, bf=0: f32) ----
__device__ inline float ldf(const void* p, size_t i, int bf) {
    if (bf) return __uint_as_float(((unsigned int)((const unsigned short*)p)[i]) << 16);
    return ((const float*)p)[i];
}
__device__ inline float4 ld4(const void* p, size_t i, int bf) {   // i % 4 == 0
    if (bf) {
        uint2 ab = *(const uint2*)((const unsigned short*)p + i);
        float4 r;
        r.x = __uint_as_float(ab.x << 16);
        r.y = __uint_as_float(ab.x & 0xffff0000u);
        r.z = __uint_as_float(ab.y << 16);
        r.w = __uint_as_float(ab.y & 0xffff0000u);
        return r;
    }
    return *(const float4*)((const float*)p + i);
}
__device__ inline float cvt(float v) { return v; }
__device__ inline float cvt(__hip_bfloat16 v) { return __bfloat162float(v); }

// ---- probe: edge int64-ness (flags[0]) and float bf16-ness (flags[1]) ----
__global__ void k_probe(const int* __restrict__ ei32, const unsigned int* __restrict__ Xw,
                        int* __restrict__ flags)
{
    __shared__ int s_edge_any, s_bf_hits;
    const int t = threadIdx.x;
    if (t == 0) { s_edge_any = 0; s_bf_hits = 0; }
    __syncthreads();
    int acc = 0;
    #pragma unroll
    for (int j = 0; j < 64; ++j) {
        int k = (t + 256 * j) * 195;                 // < EE
        acc |= ei32[2 * (size_t)k + 1];
    }
    if (acc) atomicOr(&s_edge_any, 1);
    unsigned int lo = Xw[t] & 0xffffu;
    int e = (int)((lo >> 7) & 0xff);
    if (lo == 0u || (e >= 100 && e <= 140)) atomicAdd(&s_bf_hits, 1);
    __syncthreads();
    if (t == 0) {
        flags[0] = (s_edge_any == 0) ? 1 : 0;   // 1 = int64 edges
        flags[1] = (s_bf_hits >= 192) ? 1 : 0;  // 1 = bf16 floats
    }
}

// ---- edge decode ----
__device__ inline void edge_sd(const int* ei, int e, int i64, int& s, int& d) {
    if (i64) { s = ei[2 * (size_t)e]; d = ei[2 * ((size_t)EE + e)]; }
    else     { s = ei[e];             d = ei[(size_t)EE + e]; }
    s = min(max(s, 0), NN - 1);
    d = min(max(d, 0), NN - 1);
}

// ---- degree + sum(T[src]) per dst ----
__global__ void k_norm(const int* __restrict__ ei, const int* __restrict__ flags,
                       const void* __restrict__ T,
                       float* __restrict__ cnt, float* __restrict__ sumT)
{
    int e = blockIdx.x * 256 + threadIdx.x;
    if (e >= EE) return;
    int s, d;
    edge_sd(ei, e, flags[0], s, d);
    unsafeAtomicAdd(&cnt[d], 1.0f);
    unsafeAtomicAdd(&sumT[d], ldf(T, s, flags[1]));
}

// ---- GEMM1: phi = relu(X @ Wphi + bphi).  LDS: 32+16 = 48 KB ----
__global__ __launch_bounds__(256) void k_phi(const void* __restrict__ X,
    const void* __restrict__ W, const void* __restrict__ b,
    const int* __restrict__ flags, float* __restrict__ phi)
{
    __shared__ float Wl[64 * HH];
    __shared__ float Xt[KXD][16];
    const int bf = flags[1];
    const int t = threadIdx.x;
    const int row0 = blockIdx.x * 16;

    for (int i = t; i < 16 * (KXD / 4); i += 256) {
        int r = i & 15, kq = i >> 4;
        float4 v = ld4(X, (size_t)(row0 + r) * KXD + kq * 4, bf);
        Xt[kq * 4 + 0][r] = v.x; Xt[kq * 4 + 1][r] = v.y;
        Xt[kq * 4 + 2][r] = v.z; Xt[kq * 4 + 3][r] = v.w;
    }

    const int col2  = (t & 63) * 2;
    const int rbase = (t >> 6) * 4;
    float acc[4][2] = {};

    for (int ch = 0; ch < 4; ++ch) {
        __syncthreads();
        for (int i = t * 4; i < 64 * HH; i += 256 * 4)
            *(float4*)&Wl[i] = ld4(W, (size_t)ch * 64 * HH + i, bf);
        __syncthreads();
        #pragma unroll 4
        for (int k = 0; k < 64; ++k) {
            float2 w = *(const float2*)&Wl[k * HH + col2];
            float4 x = *(const float4*)&Xt[ch * 64 + k][rbase];
            acc[0][0] += x.x * w.x; acc[0][1] += x.x * w.y;
            acc[1][0] += x.y * w.x; acc[1][1] += x.y * w.y;
            acc[2][0] += x.z * w.x; acc[2][1] += x.z * w.y;
            acc[3][0] += x.w * w.x; acc[3][1] += x.w * w.y;
        }
    }
    float bx = ldf(b, col2, bf), by = ldf(b, col2 + 1, bf);
    #pragma unroll
    for (int r = 0; r < 4; ++r) {
        int row = row0 + rbase + r;
        float2 o;
        o.x = fmaxf(acc[r][0] + bx, 0.f);
        o.y = fmaxf(acc[r][1] + by, 0.f);
        *(float2*)&phi[(size_t)row * HH + col2] = o;
    }
}

// ---- GEMM2: h = (T .* phi) @ Wgcn.  LDS: 32+8 = 40 KB ----
__global__ __launch_bounds__(256) void k_gcn(const float* __restrict__ phi,
    const void* __restrict__ T, const void* __restrict__ W,
    const int* __restrict__ flags, float* __restrict__ h)
{
    __shared__ float Wl[64 * GG];
    __shared__ float Xt[HH][16];
    const int bf = flags[1];
    const int t = threadIdx.x;
    const int row0 = blockIdx.x * 16;

    for (int i = t; i < 16 * (HH / 4); i += 256) {
        int r = i & 15, kq = i >> 4;
        float tv = ldf(T, row0 + r, bf);
        float4 v = *(const float4*)&phi[(size_t)(row0 + r) * HH + kq * 4];
        Xt[kq * 4 + 0][r] = v.x * tv; Xt[kq * 4 + 1][r] = v.y * tv;
        Xt[kq * 4 + 2][r] = v.z * tv; Xt[kq * 4 + 3][r] = v.w * tv;
    }

    const int col2  = (t & 63) * 2;
    const int rbase = (t >> 6) * 4;
    float acc[4][2] = {};

    for (int ch = 0; ch < 2; ++ch) {
        __syncthreads();
        for (int i = t * 4; i < 64 * GG; i += 256 * 4)
            *(float4*)&Wl[i] = ld4(W, (size_t)ch * 64 * GG + i, bf);
        __syncthreads();
        #pragma unroll 4
        for (int k = 0; k < 64; ++k) {
            float2 w = *(const float2*)&Wl[k * GG + col2];
            float4 x = *(const float4*)&Xt[ch * 64 + k][rbase];
            acc[0][0] += x.x * w.x; acc[0][1] += x.x * w.y;
            acc[1][0] += x.y * w.x; acc[1][1] += x.y * w.y;
            acc[2][0] += x.z * w.x; acc[2][1] += x.z * w.y;
            acc[3][0] += x.w * w.x; acc[3][1] += x.w * w.y;
        }
    }
    #pragma unroll
    for (int r = 0; r < 4; ++r) {
        int row = row0 + rbase + r;
        float2 o; o.x = acc[r][0]; o.y = acc[r][1];
        *(float2*)&h[(size_t)row * GG + col2] = o;
    }
}

// ---- per-node: dis, 1/deg, z ----
__global__ void k_prep(const float* __restrict__ cnt, const float* __restrict__ sumT,
                       float* __restrict__ dis, float* __restrict__ inv,
                       float* __restrict__ z)
{
    int i = blockIdx.x * 256 + threadIdx.x;
    if (i < NN) {
        float c = cnt[i];
        dis[i] = rsqrtf(c + 1.f);
        inv[i] = 1.f / (c + 1.f);
        z[i]   = sumT[i] / fmaxf(c, 1.f);
    }
}

// ---- CSR alloc: block-scan degrees, one atomic per block ----
__global__ __launch_bounds__(256) void k_alloc(const float* __restrict__ cnt,
    int* __restrict__ start, int* __restrict__ cur, int* __restrict__ total)
{
    __shared__ int sd[256];
    __shared__ int base;
    const int t = threadIdx.x;
    const int i = blockIdx.x * 256 + t;
    int d = (i < NN) ? (int)cnt[i] : 0;
    sd[t] = d;
    __syncthreads();
    #pragma unroll
    for (int off = 1; off < 256; off <<= 1) {
        int v = (t >= off) ? sd[t - off] : 0;
        __syncthreads();
        sd[t] += v;
        __syncthreads();
    }
    if (t == 255) base = atomicAdd(total, sd[255]);
    __syncthreads();
    if (i < NN) {
        int excl = base + sd[t] - d;
        start[i] = excl;
        cur[i]   = excl;
    }
}

// ---- CSR fill: col + per-edge coef ----
__global__ void k_fill(const int* __restrict__ ei, const int* __restrict__ flags,
                       const float* __restrict__ dis,
                       int* __restrict__ cur, int* __restrict__ col,
                       float* __restrict__ coefE)
{
    int e = blockIdx.x * 256 + threadIdx.x;
    if (e >= EE) return;
    int s, d;
    edge_sd(ei, e, flags[0], s, d);
    int pos = atomicAdd(&cur[d], 1);
    col[pos]   = s;
    coefE[pos] = dis[s] * dis[d];
}

// ---- gather-reduce + fused finalize: one block (128 thr) per node ----
__global__ __launch_bounds__(128) void k_gather(const float* __restrict__ h,
    const int* __restrict__ col, const float* __restrict__ coefE,
    const int* __restrict__ start, const float* __restrict__ cnt,
    const float* __restrict__ phi, const float* __restrict__ inv,
    const float* __restrict__ z, const void* __restrict__ bg,
    const int* __restrict__ flags,
    float* __restrict__ repg, float* __restrict__ out_rep)
{
    const int n = blockIdx.x;
    const int c = threadIdx.x;          // channel 0..127
    const int s0 = start[n];
    const int dg = (int)cnt[n];
    const int end = s0 + dg;

    float a0 = 0.f, a1 = 0.f, a2 = 0.f, a3 = 0.f;
    int j = s0;
    for (; j + 3 < end; j += 4) {
        int   i0 = col[j],     i1 = col[j + 1], i2 = col[j + 2], i3 = col[j + 3];
        float c0 = coefE[j],   c1 = coefE[j + 1], c2 = coefE[j + 2], c3 = coefE[j + 3];
        a0 += h[(size_t)i0 * GG + c] * c0;
        a1 += h[(size_t)i1 * GG + c] * c1;
        a2 += h[(size_t)i2 * GG + c] * c2;
        a3 += h[(size_t)i3 * GG + c] * c3;
    }
    for (; j < end; ++j)
        a0 += h[(size_t)col[j] * GG + c] * coefE[j];
    float acc = (a0 + a1) + (a2 + a3);

    float val = acc + h[(size_t)n * GG + c] * inv[n] + ldf(bg, c, flags[1]);
    float rg  = fmaxf(val, 0.f);
    repg[(size_t)n * GG + c] = rg;

    const size_t ob = (size_t)n * DD;
    out_rep[ob + c]      = phi[(size_t)n * HH + c];
    out_rep[ob + HH + c] = rg;
    if (c == 0) out_rep[ob + 256] = z[n];
}

// ---- fused heads, templated on weight element type; f32 output ----
template <typename ET>
__device__ void heads_body(const ET* __restrict__ W00, const ET* __restrict__ b00,
    const ET* __restrict__ W10, const ET* __restrict__ b10,
    const ET* __restrict__ W01, const ET* __restrict__ b01,
    const ET* __restrict__ W11, const ET* __restrict__ b11,
    float* __restrict__ out, float (*rp)[16], float (*wred)[16],
    float* e256, int row0, int t)
{
    const int lane = t & 63, wid = t >> 6;
    #pragma unroll 1
    for (int head = 0; head < 2; ++head) {
        const ET* WH = head ? W10 : W00;
        const ET* bH = head ? b10 : b00;
        const ET* WV = head ? W11 : W01;
        const float bV = cvt(head ? b11[0] : b01[0]);

        float bcol = cvt(bH[t]);
        float acc[16];
        #pragma unroll
        for (int r = 0; r < 16; ++r) acc[r] = bcol;

        #pragma unroll 4
        for (int k = 0; k < DD; ++k) {
            float w = cvt(WH[(size_t)k * DD + t]);
            float4 x0 = *(const float4*)&rp[k][0];
            float4 x1 = *(const float4*)&rp[k][4];
            float4 x2 = *(const float4*)&rp[k][8];
            float4 x3 = *(const float4*)&rp[k][12];
            acc[0]  += x0.x * w; acc[1]  += x0.y * w; acc[2]  += x0.z * w; acc[3]  += x0.w * w;
            acc[4]  += x1.x * w; acc[5]  += x1.y * w; acc[6]  += x1.z * w; acc[7]  += x1.w * w;
            acc[8]  += x2.x * w; acc[9]  += x2.y * w; acc[10] += x2.z * w; acc[11] += x2.w * w;
            acc[12] += x3.x * w; acc[13] += x3.y * w; acc[14] += x3.z * w; acc[15] += x3.w * w;
        }

        if (t < 16) {   // column 256
            float a = cvt(bH[256]);
            for (int k = 0; k < DD; ++k) a += rp[k][t] * cvt(WH[(size_t)k * DD + 256]);
            e256[t] = fmaxf(a, 0.f) * cvt(WV[256]);
        }

        float wv = cvt(WV[t]);
        #pragma unroll
        for (int r = 0; r < 16; ++r) {
            float v = fmaxf(acc[r], 0.f) * wv;
            #pragma unroll
            for (int off = 32; off > 0; off >>= 1) v += __shfl_down(v, off);
            if (lane == 0) wred[wid][r] = v;
        }
        __syncthreads();
        if (t < 16) {
            float y = wred[0][t] + wred[1][t] + wred[2][t] + wred[3][t] + e256[t] + bV;
            out[(size_t)head * NN + row0 + t] = y;
        }
        __syncthreads();
    }
}

__global__ __launch_bounds__(256) void k_heads(const float* __restrict__ phi,
    const float* __restrict__ repg, const float* __restrict__ z,
    const void* W00, const void* b00, const void* W10, const void* b10,
    const void* W01, const void* b01, const void* W11, const void* b11,
    const int* __restrict__ flags, float* __restrict__ out)
{
    __shared__ float rp[DD][16];
    __shared__ float wred[4][16];
    __shared__ float e256[16];
    const int t = threadIdx.x;
    const int row0 = blockIdx.x * 16;

    for (int i = t; i < 16 * DD; i += 256) {
        int r = i / DD, k = i - r * DD;
        float v;
        if (k < HH)            v = phi[(size_t)(row0 + r) * HH + k];
        else if (k < HH + GG)  v = repg[(size_t)(row0 + r) * GG + (k - HH)];
        else                   v = z[row0 + r];
        rp[k][r] = v;
    }
    __syncthreads();

    if (flags[1])
        heads_body<__hip_bfloat16>((const __hip_bfloat16*)W00, (const __hip_bfloat16*)b00,
            (const __hip_bfloat16*)W10, (const __hip_bfloat16*)b10,
            (const __hip_bfloat16*)W01, (const __hip_bfloat16*)b01,
            (const __hip_bfloat16*)W11, (const __hip_bfloat16*)b11,
            out, rp, wred, e256, row0, t);
    else
        heads_body<float>((const float*)W00, (const float*)b00,
            (const float*)W10, (const float*)b10,
            (const float*)W01, (const float*)b01,
            (const float*)W11, (const float*)b11,
            out, rp, wred, e256, row0, t);
}

extern "C" void kernel_launch(void* const* d_in, const int* in_sizes, int n_in,
                              void* d_out, int out_size, void* d_ws, size_t ws_size,
                              hipStream_t stream)
{
    const void* X    = d_in[0];
    const void* T    = d_in[1];
    const int*  ei   = (const int*)d_in[2];
    const void* Wphi = d_in[3];
    const void* bphi = d_in[4];
    const void* Wgcn = d_in[5];
    const void* bgcn = d_in[6];
    const void* W00  = d_in[7];
    const void* b00  = d_in[8];
    const void* W10  = d_in[9];
    const void* b10  = d_in[10];
    const void* W01  = d_in[11];
    const void* b01  = d_in[12];
    const void* W11  = d_in[13];
    const void* b11  = d_in[14];
    float* out = (float*)d_out;                // f32 output

    float* ws   = (float*)d_ws;
    float* phi  = ws;                          // N*H f32
    float* h    = phi  + (size_t)NN * HH;      // N*G f32
    float* repg = h    + (size_t)NN * GG;      // N*G f32
    float* cnt  = repg + (size_t)NN * GG;      // N
    float* sumT = cnt  + NN;                   // N
    float* dis  = sumT + NN;                   // N
    float* inv  = dis  + NN;                   // N
    float* z    = inv  + NN;                   // N
    float* coefE= z    + NN;                   // E
    int*   col  = (int*)(coefE + EE);          // E
    int*   start= col  + EE;                   // N
    int*   cur  = start+ NN;                   // N
    int*   flags= cur  + NN;                   // 2
    int*   total= flags+ 2;                    // 1

    // zero: cnt, sumT (contiguous) and total
    hipMemsetAsync(cnt, 0, 2 * (size_t)NN * sizeof(float), stream);
    hipMemsetAsync(total, 0, sizeof(int), stream);

    k_probe <<<1,                  256, 0, stream>>>(ei, (const unsigned int*)X, flags);
    k_norm  <<<(EE + 255) / 256,   256, 0, stream>>>(ei, flags, T, cnt, sumT);
    k_phi   <<<NN / 16,            256, 0, stream>>>(X, Wphi, bphi, flags, phi);
    k_gcn   <<<NN / 16,            256, 0, stream>>>(phi, T, Wgcn, flags, h);
    k_prep  <<<(NN + 255) / 256,   256, 0, stream>>>(cnt, sumT, dis, inv, z);
    k_alloc <<<(NN + 255) / 256,   256, 0, stream>>>(cnt, start, cur, total);
    k_fill  <<<(EE + 255) / 256,   256, 0, stream>>>(ei, flags, dis, cur, col, coefE);
    k_gather<<<NN,                 128, 0, stream>>>(h, col, coefE, start, cnt, phi,
                                                     inv, z, bgcn, flags,
                                                     repg, out + 2 * (size_t)NN);
    k_heads <<<NN / 16,            256, 0, stream>>>(phi, repg, z, W00, b00, W10, b10,
                                                     W01, b01, W11, b11, flags, out);
}

// Round 7
// 1339.627 us; speedup vs baseline: 5.0717x; 1.3119x over previous
//
#include <hip/hip_runtime.h>
#include <hip/hip_bf16.h>

#define NN 100000
#define EE 3200000
#define KXD 256
#define HH 128
#define GG 128
#define DD 257

// head-GEMM MFMA tiling
#define NT 17          // n tiles of 16  -> 272 cols (257 used)
#define KT 9           // k tiles of 32  -> 288 rows (258 used: 257 + bias row)
#define KP 288
#define SROW 296       // ushort stride for As rows (592 B, 16B aligned)

typedef __attribute__((ext_vector_type(8))) short short8;
typedef __attribute__((ext_vector_type(4))) float f32x4;

// ---- dtype-generic load helpers (bf=1: packed bf16, bf=0: f32) ----
__device__ inline float ldf(const void* p, size_t i, int bf) {
    if (bf) return __uint_as_float(((unsigned int)((const unsigned short*)p)[i]) << 16);
    return ((const float*)p)[i];
}
__device__ inline float4 ld4(const void* p, size_t i, int bf) {   // i % 4 == 0
    if (bf) {
        uint2 ab = *(const uint2*)((const unsigned short*)p + i);
        float4 r;
        r.x = __uint_as_float(ab.x << 16);
        r.y = __uint_as_float(ab.x & 0xffff0000u);
        r.z = __uint_as_float(ab.y << 16);
        r.w = __uint_as_float(ab.y & 0xffff0000u);
        return r;
    }
    return *(const float4*)((const float*)p + i);
}
__device__ inline unsigned short f2bf(float v) {   // RNE f32 -> bf16 bits
    unsigned int u = __float_as_uint(v);
    return (unsigned short)((u + 0x7fff + ((u >> 16) & 1)) >> 16);
}

// ---- probe: edge int64-ness (flags[0]) and float bf16-ness (flags[1]) ----
__global__ void k_probe(const int* __restrict__ ei32, const unsigned int* __restrict__ Xw,
                        int* __restrict__ flags)
{
    __shared__ int s_edge_any, s_bf_hits;
    const int t = threadIdx.x;
    if (t == 0) { s_edge_any = 0; s_bf_hits = 0; }
    __syncthreads();
    int acc = 0;
    #pragma unroll
    for (int j = 0; j < 64; ++j) {
        int k = (t + 256 * j) * 195;                 // < EE
        acc |= ei32[2 * (size_t)k + 1];
    }
    if (acc) atomicOr(&s_edge_any, 1);
    unsigned int lo = Xw[t] & 0xffffu;
    int e = (int)((lo >> 7) & 0xff);
    if (lo == 0u || (e >= 100 && e <= 140)) atomicAdd(&s_bf_hits, 1);
    __syncthreads();
    if (t == 0) {
        flags[0] = (s_edge_any == 0) ? 1 : 0;   // 1 = int64 edges
        flags[1] = (s_bf_hits >= 192) ? 1 : 0;  // 1 = bf16 floats
    }
}

// ---- edge decode ----
__device__ inline void edge_sd(const int* ei, int e, int i64, int& s, int& d) {
    if (i64) { s = ei[2 * (size_t)e]; d = ei[2 * ((size_t)EE + e)]; }
    else     { s = ei[e];             d = ei[(size_t)EE + e]; }
    s = min(max(s, 0), NN - 1);
    d = min(max(d, 0), NN - 1);
}

// ---- degree + sum(T[src]) per dst ----
__global__ void k_norm(const int* __restrict__ ei, const int* __restrict__ flags,
                       const void* __restrict__ T,
                       float* __restrict__ cnt, float* __restrict__ sumT)
{
    int e = blockIdx.x * 256 + threadIdx.x;
    if (e >= EE) return;
    int s, d;
    edge_sd(ei, e, flags[0], s, d);
    unsafeAtomicAdd(&cnt[d], 1.0f);
    unsafeAtomicAdd(&sumT[d], ldf(T, s, flags[1]));
}

// ---- GEMM1: phi = relu(X @ Wphi + bphi).  LDS: 32+16 = 48 KB ----
__global__ __launch_bounds__(256) void k_phi(const void* __restrict__ X,
    const void* __restrict__ W, const void* __restrict__ b,
    const int* __restrict__ flags, float* __restrict__ phi)
{
    __shared__ float Wl[64 * HH];
    __shared__ float Xt[KXD][16];
    const int bf = flags[1];
    const int t = threadIdx.x;
    const int row0 = blockIdx.x * 16;

    for (int i = t; i < 16 * (KXD / 4); i += 256) {
        int r = i & 15, kq = i >> 4;
        float4 v = ld4(X, (size_t)(row0 + r) * KXD + kq * 4, bf);
        Xt[kq * 4 + 0][r] = v.x; Xt[kq * 4 + 1][r] = v.y;
        Xt[kq * 4 + 2][r] = v.z; Xt[kq * 4 + 3][r] = v.w;
    }

    const int col2  = (t & 63) * 2;
    const int rbase = (t >> 6) * 4;
    float acc[4][2] = {};

    for (int ch = 0; ch < 4; ++ch) {
        __syncthreads();
        for (int i = t * 4; i < 64 * HH; i += 256 * 4)
            *(float4*)&Wl[i] = ld4(W, (size_t)ch * 64 * HH + i, bf);
        __syncthreads();
        #pragma unroll 4
        for (int k = 0; k < 64; ++k) {
            float2 w = *(const float2*)&Wl[k * HH + col2];
            float4 x = *(const float4*)&Xt[ch * 64 + k][rbase];
            acc[0][0] += x.x * w.x; acc[0][1] += x.x * w.y;
            acc[1][0] += x.y * w.x; acc[1][1] += x.y * w.y;
            acc[2][0] += x.z * w.x; acc[2][1] += x.z * w.y;
            acc[3][0] += x.w * w.x; acc[3][1] += x.w * w.y;
        }
    }
    float bx = ldf(b, col2, bf), by = ldf(b, col2 + 1, bf);
    #pragma unroll
    for (int r = 0; r < 4; ++r) {
        int row = row0 + rbase + r;
        float2 o;
        o.x = fmaxf(acc[r][0] + bx, 0.f);
        o.y = fmaxf(acc[r][1] + by, 0.f);
        *(float2*)&phi[(size_t)row * HH + col2] = o;
    }
}

// ---- GEMM2: h = (T .* phi) @ Wgcn.  LDS: 32+8 = 40 KB ----
__global__ __launch_bounds__(256) void k_gcn(const float* __restrict__ phi,
    const void* __restrict__ T, const void* __restrict__ W,
    const int* __restrict__ flags, float* __restrict__ h)
{
    __shared__ float Wl[64 * GG];
    __shared__ float Xt[HH][16];
    const int bf = flags[1];
    const int t = threadIdx.x;
    const int row0 = blockIdx.x * 16;

    for (int i = t; i < 16 * (HH / 4); i += 256) {
        int r = i & 15, kq = i >> 4;
        float tv = ldf(T, row0 + r, bf);
        float4 v = *(const float4*)&phi[(size_t)(row0 + r) * HH + kq * 4];
        Xt[kq * 4 + 0][r] = v.x * tv; Xt[kq * 4 + 1][r] = v.y * tv;
        Xt[kq * 4 + 2][r] = v.z * tv; Xt[kq * 4 + 3][r] = v.w * tv;
    }

    const int col2  = (t & 63) * 2;
    const int rbase = (t >> 6) * 4;
    float acc[4][2] = {};

    for (int ch = 0; ch < 2; ++ch) {
        __syncthreads();
        for (int i = t * 4; i < 64 * GG; i += 256 * 4)
            *(float4*)&Wl[i] = ld4(W, (size_t)ch * 64 * GG + i, bf);
        __syncthreads();
        #pragma unroll 4
        for (int k = 0; k < 64; ++k) {
            float2 w = *(const float2*)&Wl[k * GG + col2];
            float4 x = *(const float4*)&Xt[ch * 64 + k][rbase];
            acc[0][0] += x.x * w.x; acc[0][1] += x.x * w.y;
            acc[1][0] += x.y * w.x; acc[1][1] += x.y * w.y;
            acc[2][0] += x.z * w.x; acc[2][1] += x.z * w.y;
            acc[3][0] += x.w * w.x; acc[3][1] += x.w * w.y;
        }
    }
    #pragma unroll
    for (int r = 0; r < 4; ++r) {
        int row = row0 + rbase + r;
        float2 o; o.x = acc[r][0]; o.y = acc[r][1];
        *(float2*)&h[(size_t)row * GG + col2] = o;
    }
}

// ---- per-node: dis, 1/deg, z ----
__global__ void k_prep(const float* __restrict__ cnt, const float* __restrict__ sumT,
                       float* __restrict__ dis, float* __restrict__ inv,
                       float* __restrict__ z)
{
    int i = blockIdx.x * 256 + threadIdx.x;
    if (i < NN) {
        float c = cnt[i];
        dis[i] = rsqrtf(c + 1.f);
        inv[i] = 1.f / (c + 1.f);
        z[i]   = sumT[i] / fmaxf(c, 1.f);
    }
}

// ---- CSR alloc: block-scan degrees, one atomic per block ----
__global__ __launch_bounds__(256) void k_alloc(const float* __restrict__ cnt,
    int* __restrict__ start, int* __restrict__ cur, int* __restrict__ total)
{
    __shared__ int sd[256];
    __shared__ int base;
    const int t = threadIdx.x;
    const int i = blockIdx.x * 256 + t;
    int d = (i < NN) ? (int)cnt[i] : 0;
    sd[t] = d;
    __syncthreads();
    #pragma unroll
    for (int off = 1; off < 256; off <<= 1) {
        int v = (t >= off) ? sd[t - off] : 0;
        __syncthreads();
        sd[t] += v;
        __syncthreads();
    }
    if (t == 255) base = atomicAdd(total, sd[255]);
    __syncthreads();
    if (i < NN) {
        int excl = base + sd[t] - d;
        start[i] = excl;
        cur[i]   = excl;
    }
}

// ---- CSR fill: col + per-edge coef ----
__global__ void k_fill(const int* __restrict__ ei, const int* __restrict__ flags,
                       const float* __restrict__ dis,
                       int* __restrict__ cur, int* __restrict__ col,
                       float* __restrict__ coefE)
{
    int e = blockIdx.x * 256 + threadIdx.x;
    if (e >= EE) return;
    int s, d;
    edge_sd(ei, e, flags[0], s, d);
    int pos = atomicAdd(&cur[d], 1);
    col[pos]   = s;
    coefE[pos] = dis[s] * dis[d];
}

// ---- gather-reduce + fused finalize: one block (128 thr) per node ----
__global__ __launch_bounds__(128) void k_gather(const float* __restrict__ h,
    const int* __restrict__ col, const float* __restrict__ coefE,
    const int* __restrict__ start, const float* __restrict__ cnt,
    const float* __restrict__ phi, const float* __restrict__ inv,
    const float* __restrict__ z, const void* __restrict__ bg,
    const int* __restrict__ flags,
    float* __restrict__ repg, float* __restrict__ out_rep)
{
    const int n = blockIdx.x;
    const int c = threadIdx.x;          // channel 0..127
    const int s0 = start[n];
    const int dg = (int)cnt[n];
    const int end = s0 + dg;

    float a0 = 0.f, a1 = 0.f, a2 = 0.f, a3 = 0.f;
    int j = s0;
    for (; j + 3 < end; j += 4) {
        int   i0 = col[j],     i1 = col[j + 1], i2 = col[j + 2], i3 = col[j + 3];
        float c0 = coefE[j],   c1 = coefE[j + 1], c2 = coefE[j + 2], c3 = coefE[j + 3];
        a0 += h[(size_t)i0 * GG + c] * c0;
        a1 += h[(size_t)i1 * GG + c] * c1;
        a2 += h[(size_t)i2 * GG + c] * c2;
        a3 += h[(size_t)i3 * GG + c] * c3;
    }
    for (; j < end; ++j)
        a0 += h[(size_t)col[j] * GG + c] * coefE[j];
    float acc = (a0 + a1) + (a2 + a3);

    float val = acc + h[(size_t)n * GG + c] * inv[n] + ldf(bg, c, flags[1]);
    float rg  = fmaxf(val, 0.f);
    repg[(size_t)n * GG + c] = rg;

    const size_t ob = (size_t)n * DD;
    out_rep[ob + c]      = phi[(size_t)n * HH + c];
    out_rep[ob + HH + c] = rg;
    if (c == 0) out_rep[ob + 256] = z[n];
}

// ---- pack head weights into MFMA B-fragment order, bf16, bias folded at k=257 ----
// Bpk[((head*NT+nt)*KT+kt)*64 + lane][j] = B[kt*32 + (lane>>4)*8 + j][nt*16 + (lane&15)]
__global__ __launch_bounds__(64) void k_pack(const void* W00, const void* b00,
    const void* W10, const void* b10, const int* __restrict__ flags,
    unsigned short* __restrict__ Bpk)
{
    const int blk  = blockIdx.x;          // head*NT*KT + nt*KT + kt
    const int lane = threadIdx.x;
    const int head = blk / (NT * KT);
    const int rem  = blk - head * NT * KT;
    const int nt   = rem / KT, kt = rem - (rem / KT) * KT;
    const void* WH = head ? W10 : W00;
    const void* bH = head ? b10 : b00;
    const int bf = flags[1];
    const int n  = nt * 16 + (lane & 15);
    const int k0 = kt * 32 + (lane >> 4) * 8;
    unsigned short v[8];
    #pragma unroll
    for (int j = 0; j < 8; ++j) {
        int k = k0 + j;
        float x = 0.f;
        if (n < DD) {
            if (k < DD)       x = ldf(WH, (size_t)k * DD + n, bf);
            else if (k == DD) x = ldf(bH, n, bf);
        }
        v[j] = f2bf(x);
    }
    *(short8*)(Bpk + ((size_t)blk * 64 + lane) * 8) = *(short8*)v;
}

// ---- MFMA heads: 32 rows/block, 2 waves (wave = head) ----
__global__ __launch_bounds__(128) void k_heads_mfma(const float* __restrict__ phi,
    const float* __restrict__ repg, const float* __restrict__ z,
    const unsigned short* __restrict__ Bpk,
    const void* W01, const void* b01, const void* W11, const void* b11,
    const int* __restrict__ flags, float* __restrict__ out)
{
    __shared__ unsigned short As[32][SROW];   // 18.9 KB bf16 A tile, K padded to 288
    const int t = threadIdx.x;
    const int row0 = blockIdx.x * 32;
    const int bf = flags[1];

    // stage A: rep rows -> bf16, k=257 is the bias-multiplier 1.0, pad zeros
    for (int i = t; i < 32 * KP; i += 128) {
        int m = i / KP, k = i - m * KP;
        int row = row0 + m;
        float v = 0.f;
        if (k < HH)           v = phi[(size_t)row * HH + k];
        else if (k < 256)     v = repg[(size_t)row * GG + (k - HH)];
        else if (k == 256)    v = z[row];
        else if (k == 257)    v = 1.0f;
        As[m][k] = f2bf(v);
    }
    __syncthreads();

    const int wave = t >> 6;         // head
    const int lane = t & 63;
    const int m = lane & 15, q = lane >> 4;

    const void* WV = wave ? W11 : W01;
    const float bV = ldf(wave ? b11 : b01, 0, bf);

    float r0[4] = {0.f, 0.f, 0.f, 0.f};   // rows row0 + q*4 + r
    float r1[4] = {0.f, 0.f, 0.f, 0.f};   // rows row0 + 16 + q*4 + r

    const unsigned short* Bh = Bpk + (size_t)wave * NT * KT * 64 * 8;
    for (int nt = 0; nt < NT; ++nt) {
        f32x4 acc0 = {0.f, 0.f, 0.f, 0.f};
        f32x4 acc1 = {0.f, 0.f, 0.f, 0.f};
        const unsigned short* Bn = Bh + (size_t)nt * KT * 64 * 8;
        #pragma unroll
        for (int kt = 0; kt < KT; ++kt) {
            short8 b  = *(const short8*)(Bn + ((size_t)kt * 64 + lane) * 8);
            short8 a0 = *(const short8*)&As[m][kt * 32 + q * 8];
            short8 a1 = *(const short8*)&As[m + 16][kt * 32 + q * 8];
            acc0 = __builtin_amdgcn_mfma_f32_16x16x32_bf16(a0, b, acc0, 0, 0, 0);
            acc1 = __builtin_amdgcn_mfma_f32_16x16x32_bf16(a1, b, acc1, 0, 0, 0);
        }
        int n = nt * 16 + m;                       // C col = lane&15
        float wv = (n < DD) ? ldf(WV, n, bf) : 0.f;
        #pragma unroll
        for (int r = 0; r < 4; ++r) {
            r0[r] += fmaxf(acc0[r], 0.f) * wv;
            r1[r] += fmaxf(acc1[r], 0.f) * wv;
        }
    }

    // reduce across the 16 cols held by lanes sharing q (xor low 4 bits)
    #pragma unroll
    for (int r = 0; r < 4; ++r) {
        #pragma unroll
        for (int off = 8; off > 0; off >>= 1) {
            r0[r] += __shfl_xor(r0[r], off);
            r1[r] += __shfl_xor(r1[r], off);
        }
    }
    if (m == 0) {
        #pragma unroll
        for (int r = 0; r < 4; ++r) {
            out[(size_t)wave * NN + row0 + q * 4 + r]      = r0[r] + bV;
            out[(size_t)wave * NN + row0 + 16 + q * 4 + r] = r1[r] + bV;
        }
    }
}

extern "C" void kernel_launch(void* const* d_in, const int* in_sizes, int n_in,
                              void* d_out, int out_size, void* d_ws, size_t ws_size,
                              hipStream_t stream)
{
    const void* X    = d_in[0];
    const void* T    = d_in[1];
    const int*  ei   = (const int*)d_in[2];
    const void* Wphi = d_in[3];
    const void* bphi = d_in[4];
    const void* Wgcn = d_in[5];
    const void* bgcn = d_in[6];
    const void* W00  = d_in[7];
    const void* b00  = d_in[8];
    const void* W10  = d_in[9];
    const void* b10  = d_in[10];
    const void* W01  = d_in[11];
    const void* b01  = d_in[12];
    const void* W11  = d_in[13];
    const void* b11  = d_in[14];
    float* out = (float*)d_out;                // f32 output

    float* ws   = (float*)d_ws;
    float* phi  = ws;                          // N*H f32
    float* h    = phi  + (size_t)NN * HH;      // N*G f32
    float* repg = h    + (size_t)NN * GG;      // N*G f32
    float* cnt  = repg + (size_t)NN * GG;      // N
    float* sumT = cnt  + NN;                   // N
    float* dis  = sumT + NN;                   // N
    float* inv  = dis  + NN;                   // N
    float* z    = inv  + NN;                   // N
    float* coefE= z    + NN;                   // E
    int*   col  = (int*)(coefE + EE);          // E
    int*   start= col  + EE;                   // N
    int*   cur  = start+ NN;                   // N
    int*   flags= cur  + NN;                   // 2
    int*   total= flags+ 2;                    // 1
    unsigned short* Bpk = (unsigned short*)(total + 1);   // 2*NT*KT*64*8 bf16

    hipMemsetAsync(cnt, 0, 2 * (size_t)NN * sizeof(float), stream);
    hipMemsetAsync(total, 0, sizeof(int), stream);

    k_probe <<<1,                  256, 0, stream>>>(ei, (const unsigned int*)X, flags);
    k_norm  <<<(EE + 255) / 256,   256, 0, stream>>>(ei, flags, T, cnt, sumT);
    k_pack  <<<2 * NT * KT,         64, 0, stream>>>(W00, b00, W10, b10, flags, Bpk);
    k_phi   <<<NN / 16,            256, 0, stream>>>(X, Wphi, bphi, flags, phi);
    k_gcn   <<<NN / 16,            256, 0, stream>>>(phi, T, Wgcn, flags, h);
    k_prep  <<<(NN + 255) / 256,   256, 0, stream>>>(cnt, sumT, dis, inv, z);
    k_alloc <<<(NN + 255) / 256,   256, 0, stream>>>(cnt, start, cur, total);
    k_fill  <<<(EE + 255) / 256,   256, 0, stream>>>(ei, flags, dis, cur, col, coefE);
    k_gather<<<NN,                 128, 0, stream>>>(h, col, coefE, start, cnt, phi,
                                                     inv, z, bgcn, flags,
                                                     repg, out + 2 * (size_t)NN);
    k_heads_mfma<<<NN / 32,        128, 0, stream>>>(phi, repg, z, Bpk,
                                                     W01, b01, W11, b11, flags, out);
}

// Round 8
// 1125.904 us; speedup vs baseline: 6.0344x; 1.1898x over previous
//
#include <hip/hip_runtime.h>
#include <hip/hip_bf16.h>

#define NN 100000
#define EE 3200000
#define KXD 256
#define HH 128
#define GG 128
#define DD 257

// head-GEMM MFMA tiling
#define NT 17          // n tiles of 16  -> 272 cols (257 used)
#define KT 9           // k tiles of 32  -> 288 rows (258 used: 257 + bias row)
#define KP 288
#define SROW 296       // ushort stride for As rows (592 B, 16B aligned)

typedef __attribute__((ext_vector_type(8))) short short8;
typedef __attribute__((ext_vector_type(4))) float f32x4;
typedef unsigned short ushort_t;

// ---- dtype-generic load helpers (bf=1: packed bf16, bf=0: f32) ----
__device__ inline float bfu2f(unsigned short u) {
    return __uint_as_float(((unsigned int)u) << 16);
}
__device__ inline float ldf(const void* p, size_t i, int bf) {
    if (bf) return bfu2f(((const unsigned short*)p)[i]);
    return ((const float*)p)[i];
}
__device__ inline float4 ld4(const void* p, size_t i, int bf) {   // i % 4 == 0
    if (bf) {
        uint2 ab = *(const uint2*)((const unsigned short*)p + i);
        float4 r;
        r.x = __uint_as_float(ab.x << 16);
        r.y = __uint_as_float(ab.x & 0xffff0000u);
        r.z = __uint_as_float(ab.y << 16);
        r.w = __uint_as_float(ab.y & 0xffff0000u);
        return r;
    }
    return *(const float4*)((const float*)p + i);
}
__device__ inline unsigned short f2bf(float v) {   // RNE f32 -> bf16 bits
    unsigned int u = __float_as_uint(v);
    return (unsigned short)((u + 0x7fff + ((u >> 16) & 1)) >> 16);
}

// ---- probe: edge int64-ness (flags[0]) and float bf16-ness (flags[1]) ----
__global__ void k_probe(const int* __restrict__ ei32, const unsigned int* __restrict__ Xw,
                        int* __restrict__ flags)
{
    __shared__ int s_edge_any, s_bf_hits;
    const int t = threadIdx.x;
    if (t == 0) { s_edge_any = 0; s_bf_hits = 0; }
    __syncthreads();
    int acc = 0;
    #pragma unroll
    for (int j = 0; j < 64; ++j) {
        int k = (t + 256 * j) * 195;                 // < EE
        acc |= ei32[2 * (size_t)k + 1];
    }
    if (acc) atomicOr(&s_edge_any, 1);
    unsigned int lo = Xw[t] & 0xffffu;
    int e = (int)((lo >> 7) & 0xff);
    if (lo == 0u || (e >= 100 && e <= 140)) atomicAdd(&s_bf_hits, 1);
    __syncthreads();
    if (t == 0) {
        flags[0] = (s_edge_any == 0) ? 1 : 0;   // 1 = int64 edges
        flags[1] = (s_bf_hits >= 192) ? 1 : 0;  // 1 = bf16 floats
    }
}

// ---- edge decode ----
__device__ inline void edge_sd(const int* ei, int e, int i64, int& s, int& d) {
    if (i64) { s = ei[2 * (size_t)e]; d = ei[2 * ((size_t)EE + e)]; }
    else     { s = ei[e];             d = ei[(size_t)EE + e]; }
    s = min(max(s, 0), NN - 1);
    d = min(max(d, 0), NN - 1);
}

// ---- per-edge degree count (int atomics) ----
__global__ void k_count(const int* __restrict__ ei, const int* __restrict__ flags,
                        int* __restrict__ cntI)
{
    int e = blockIdx.x * 256 + threadIdx.x;
    if (e >= EE) return;
    int s, d;
    edge_sd(ei, e, flags[0], s, d);
    atomicAdd(&cntI[d], 1);
}

// ---- GEMM1: phi = relu(X @ Wphi + bphi).  LDS: 32+16 = 48 KB ----
__global__ __launch_bounds__(256) void k_phi(const void* __restrict__ X,
    const void* __restrict__ W, const void* __restrict__ b,
    const int* __restrict__ flags, float* __restrict__ phi)
{
    __shared__ float Wl[64 * HH];
    __shared__ float Xt[KXD][16];
    const int bf = flags[1];
    const int t = threadIdx.x;
    const int row0 = blockIdx.x * 16;

    for (int i = t; i < 16 * (KXD / 4); i += 256) {
        int r = i & 15, kq = i >> 4;
        float4 v = ld4(X, (size_t)(row0 + r) * KXD + kq * 4, bf);
        Xt[kq * 4 + 0][r] = v.x; Xt[kq * 4 + 1][r] = v.y;
        Xt[kq * 4 + 2][r] = v.z; Xt[kq * 4 + 3][r] = v.w;
    }

    const int col2  = (t & 63) * 2;
    const int rbase = (t >> 6) * 4;
    float acc[4][2] = {};

    for (int ch = 0; ch < 4; ++ch) {
        __syncthreads();
        for (int i = t * 4; i < 64 * HH; i += 256 * 4)
            *(float4*)&Wl[i] = ld4(W, (size_t)ch * 64 * HH + i, bf);
        __syncthreads();
        #pragma unroll 4
        for (int k = 0; k < 64; ++k) {
            float2 w = *(const float2*)&Wl[k * HH + col2];
            float4 x = *(const float4*)&Xt[ch * 64 + k][rbase];
            acc[0][0] += x.x * w.x; acc[0][1] += x.x * w.y;
            acc[1][0] += x.y * w.x; acc[1][1] += x.y * w.y;
            acc[2][0] += x.z * w.x; acc[2][1] += x.z * w.y;
            acc[3][0] += x.w * w.x; acc[3][1] += x.w * w.y;
        }
    }
    float bx = ldf(b, col2, bf), by = ldf(b, col2 + 1, bf);
    #pragma unroll
    for (int r = 0; r < 4; ++r) {
        int row = row0 + rbase + r;
        float2 o;
        o.x = fmaxf(acc[r][0] + bx, 0.f);
        o.y = fmaxf(acc[r][1] + by, 0.f);
        *(float2*)&phi[(size_t)row * HH + col2] = o;
    }
}

// ---- GEMM2: h = (T .* phi) @ Wgcn -> bf16.  LDS: 32+8 = 40 KB ----
__global__ __launch_bounds__(256) void k_gcn(const float* __restrict__ phi,
    const void* __restrict__ T, const void* __restrict__ W,
    const int* __restrict__ flags, ushort_t* __restrict__ h)
{
    __shared__ float Wl[64 * GG];
    __shared__ float Xt[HH][16];
    const int bf = flags[1];
    const int t = threadIdx.x;
    const int row0 = blockIdx.x * 16;

    for (int i = t; i < 16 * (HH / 4); i += 256) {
        int r = i & 15, kq = i >> 4;
        float tv = ldf(T, row0 + r, bf);
        float4 v = *(const float4*)&phi[(size_t)(row0 + r) * HH + kq * 4];
        Xt[kq * 4 + 0][r] = v.x * tv; Xt[kq * 4 + 1][r] = v.y * tv;
        Xt[kq * 4 + 2][r] = v.z * tv; Xt[kq * 4 + 3][r] = v.w * tv;
    }

    const int col2  = (t & 63) * 2;
    const int rbase = (t >> 6) * 4;
    float acc[4][2] = {};

    for (int ch = 0; ch < 2; ++ch) {
        __syncthreads();
        for (int i = t * 4; i < 64 * GG; i += 256 * 4)
            *(float4*)&Wl[i] = ld4(W, (size_t)ch * 64 * GG + i, bf);
        __syncthreads();
        #pragma unroll 4
        for (int k = 0; k < 64; ++k) {
            float2 w = *(const float2*)&Wl[k * GG + col2];
            float4 x = *(const float4*)&Xt[ch * 64 + k][rbase];
            acc[0][0] += x.x * w.x; acc[0][1] += x.x * w.y;
            acc[1][0] += x.y * w.x; acc[1][1] += x.y * w.y;
            acc[2][0] += x.z * w.x; acc[2][1] += x.z * w.y;
            acc[3][0] += x.w * w.x; acc[3][1] += x.w * w.y;
        }
    }
    #pragma unroll
    for (int r = 0; r < 4; ++r) {
        int row = row0 + rbase + r;
        unsigned int packed = (unsigned int)f2bf(acc[r][0])
                            | ((unsigned int)f2bf(acc[r][1]) << 16);
        *(unsigned int*)&h[(size_t)row * GG + col2] = packed;
    }
}

// ---- per-node: dis, 1/deg ----
__global__ void k_prep(const int* __restrict__ cntI,
                       float* __restrict__ dis, float* __restrict__ inv)
{
    int i = blockIdx.x * 256 + threadIdx.x;
    if (i < NN) {
        float c = (float)cntI[i];
        dis[i] = rsqrtf(c + 1.f);
        inv[i] = 1.f / (c + 1.f);
    }
}

// ---- CSR alloc: block-scan degrees, one atomic per block ----
__global__ __launch_bounds__(256) void k_alloc(const int* __restrict__ cntI,
    int* __restrict__ start, int* __restrict__ cur, int* __restrict__ total)
{
    __shared__ int sd[256];
    __shared__ int base;
    const int t = threadIdx.x;
    const int i = blockIdx.x * 256 + t;
    int d = (i < NN) ? cntI[i] : 0;
    sd[t] = d;
    __syncthreads();
    #pragma unroll
    for (int off = 1; off < 256; off <<= 1) {
        int v = (t >= off) ? sd[t - off] : 0;
        __syncthreads();
        sd[t] += v;
        __syncthreads();
    }
    if (t == 255) base = atomicAdd(total, sd[255]);
    __syncthreads();
    if (i < NN) {
        int excl = base + sd[t] - d;
        start[i] = excl;
        cur[i]   = excl;
    }
}

// ---- CSR fill: packed (col, coef) int2, one 8B write per edge ----
__global__ void k_fill(const int* __restrict__ ei, const int* __restrict__ flags,
                       const float* __restrict__ dis,
                       int* __restrict__ cur, int2* __restrict__ cs)
{
    int e = blockIdx.x * 256 + threadIdx.x;
    if (e >= EE) return;
    int s, d;
    edge_sd(ei, e, flags[0], s, d);
    int pos = atomicAdd(&cur[d], 1);
    int2 v;
    v.x = s;
    v.y = __float_as_int(dis[s] * dis[d]);
    cs[pos] = v;
}

// ---- gather-reduce + z + fused finalize: one block (128 thr) per node ----
__global__ __launch_bounds__(128) void k_gather(const ushort_t* __restrict__ h,
    const int2* __restrict__ cs, const int* __restrict__ start,
    const int* __restrict__ cntI, const void* __restrict__ T,
    const float* __restrict__ phi, const float* __restrict__ inv,
    const void* __restrict__ bg, const int* __restrict__ flags,
    float* __restrict__ z, ushort_t* __restrict__ repg_bf,
    float* __restrict__ out_rep)
{
    const int n = blockIdx.x;
    const int c = threadIdx.x;          // channel 0..127
    const int bf = flags[1];
    const int s0 = start[n];
    const int dg = cntI[n];
    const int end = s0 + dg;

    float a0 = 0.f, a1 = 0.f, a2 = 0.f, a3 = 0.f;
    float zacc = 0.f;
    int j = s0;
    for (; j + 3 < end; j += 4) {
        int2 e0 = cs[j], e1 = cs[j + 1], e2 = cs[j + 2], e3 = cs[j + 3];
        a0 += bfu2f(h[(size_t)e0.x * GG + c]) * __int_as_float(e0.y);
        a1 += bfu2f(h[(size_t)e1.x * GG + c]) * __int_as_float(e1.y);
        a2 += bfu2f(h[(size_t)e2.x * GG + c]) * __int_as_float(e2.y);
        a3 += bfu2f(h[(size_t)e3.x * GG + c]) * __int_as_float(e3.y);
        zacc += ldf(T, e0.x, bf) + ldf(T, e1.x, bf)
              + ldf(T, e2.x, bf) + ldf(T, e3.x, bf);
    }
    for (; j < end; ++j) {
        int2 e = cs[j];
        a0 += bfu2f(h[(size_t)e.x * GG + c]) * __int_as_float(e.y);
        zacc += ldf(T, e.x, bf);
    }
    float acc = (a0 + a1) + (a2 + a3);

    float val = acc + bfu2f(h[(size_t)n * GG + c]) * inv[n] + ldf(bg, c, bf);
    float rg  = fmaxf(val, 0.f);
    repg_bf[(size_t)n * GG + c] = f2bf(rg);

    const size_t ob = (size_t)n * DD;
    out_rep[ob + c]      = phi[(size_t)n * HH + c];
    out_rep[ob + HH + c] = rg;
    if (c == 0) {
        float zv = zacc / fmaxf((float)dg, 1.f);
        z[n] = zv;
        out_rep[ob + 256] = zv;
    }
}

// ---- pack head weights into MFMA B-fragment order, bf16, bias folded at k=257 ----
__global__ __launch_bounds__(64) void k_pack(const void* W00, const void* b00,
    const void* W10, const void* b10, const int* __restrict__ flags,
    unsigned short* __restrict__ Bpk)
{
    const int blk  = blockIdx.x;          // head*NT*KT + nt*KT + kt
    const int lane = threadIdx.x;
    const int head = blk / (NT * KT);
    const int rem  = blk - head * NT * KT;
    const int nt   = rem / KT, kt = rem - (rem / KT) * KT;
    const void* WH = head ? W10 : W00;
    const void* bH = head ? b10 : b00;
    const int bf = flags[1];
    const int n  = nt * 16 + (lane & 15);
    const int k0 = kt * 32 + (lane >> 4) * 8;
    unsigned short v[8];
    #pragma unroll
    for (int j = 0; j < 8; ++j) {
        int k = k0 + j;
        float x = 0.f;
        if (n < DD) {
            if (k < DD)       x = ldf(WH, (size_t)k * DD + n, bf);
            else if (k == DD) x = ldf(bH, n, bf);
        }
        v[j] = f2bf(x);
    }
    *(short8*)(Bpk + ((size_t)blk * 64 + lane) * 8) = *(short8*)v;
}

// ---- MFMA heads: 32 rows/block, 2 waves (wave = head) ----
__global__ __launch_bounds__(128) void k_heads_mfma(const float* __restrict__ phi,
    const ushort_t* __restrict__ repg_bf, const float* __restrict__ z,
    const unsigned short* __restrict__ Bpk,
    const void* W01, const void* b01, const void* W11, const void* b11,
    const int* __restrict__ flags, float* __restrict__ out)
{
    __shared__ unsigned short As[32][SROW];   // 18.9 KB bf16 A tile, K padded to 288
    const int t = threadIdx.x;
    const int row0 = blockIdx.x * 32;
    const int bf = flags[1];

    // stage A: rep rows -> bf16, k=257 is the bias-multiplier 1.0, pad zeros
    for (int i = t; i < 32 * KP; i += 128) {
        int m = i / KP, k = i - m * KP;
        int row = row0 + m;
        unsigned short v;
        if (k < HH)           v = f2bf(phi[(size_t)row * HH + k]);
        else if (k < 256)     v = repg_bf[(size_t)row * GG + (k - HH)];
        else if (k == 256)    v = f2bf(z[row]);
        else if (k == 257)    v = 0x3F80;      // 1.0 bf16
        else                  v = 0;
        As[m][k] = v;
    }
    __syncthreads();

    const int wave = t >> 6;         // head
    const int lane = t & 63;
    const int m = lane & 15, q = lane >> 4;

    const void* WV = wave ? W11 : W01;
    const float bV = ldf(wave ? b11 : b01, 0, bf);

    float r0[4] = {0.f, 0.f, 0.f, 0.f};   // rows row0 + q*4 + r
    float r1[4] = {0.f, 0.f, 0.f, 0.f};   // rows row0 + 16 + q*4 + r

    const unsigned short* Bh = Bpk + (size_t)wave * NT * KT * 64 * 8;
    for (int nt = 0; nt < NT; ++nt) {
        f32x4 acc0 = {0.f, 0.f, 0.f, 0.f};
        f32x4 acc1 = {0.f, 0.f, 0.f, 0.f};
        const unsigned short* Bn = Bh + (size_t)nt * KT * 64 * 8;
        #pragma unroll
        for (int kt = 0; kt < KT; ++kt) {
            short8 b  = *(const short8*)(Bn + ((size_t)kt * 64 + lane) * 8);
            short8 a0 = *(const short8*)&As[m][kt * 32 + q * 8];
            short8 a1 = *(const short8*)&As[m + 16][kt * 32 + q * 8];
            acc0 = __builtin_amdgcn_mfma_f32_16x16x32_bf16(a0, b, acc0, 0, 0, 0);
            acc1 = __builtin_amdgcn_mfma_f32_16x16x32_bf16(a1, b, acc1, 0, 0, 0);
        }
        int n = nt * 16 + m;                       // C col = lane&15
        float wv = (n < DD) ? ldf(WV, n, bf) : 0.f;
        #pragma unroll
        for (int r = 0; r < 4; ++r) {
            r0[r] += fmaxf(acc0[r], 0.f) * wv;
            r1[r] += fmaxf(acc1[r], 0.f) * wv;
        }
    }

    #pragma unroll
    for (int r = 0; r < 4; ++r) {
        #pragma unroll
        for (int off = 8; off > 0; off >>= 1) {
            r0[r] += __shfl_xor(r0[r], off);
            r1[r] += __shfl_xor(r1[r], off);
        }
    }
    if (m == 0) {
        #pragma unroll
        for (int r = 0; r < 4; ++r) {
            out[(size_t)wave * NN + row0 + q * 4 + r]      = r0[r] + bV;
            out[(size_t)wave * NN + row0 + 16 + q * 4 + r] = r1[r] + bV;
        }
    }
}

extern "C" void kernel_launch(void* const* d_in, const int* in_sizes, int n_in,
                              void* d_out, int out_size, void* d_ws, size_t ws_size,
                              hipStream_t stream)
{
    const void* X    = d_in[0];
    const void* T    = d_in[1];
    const int*  ei   = (const int*)d_in[2];
    const void* Wphi = d_in[3];
    const void* bphi = d_in[4];
    const void* Wgcn = d_in[5];
    const void* bgcn = d_in[6];
    const void* W00  = d_in[7];
    const void* b00  = d_in[8];
    const void* W10  = d_in[9];
    const void* b10  = d_in[10];
    const void* W01  = d_in[11];
    const void* b01  = d_in[12];
    const void* W11  = d_in[13];
    const void* b11  = d_in[14];
    float* out = (float*)d_out;                // f32 output

    char* ws = (char*)d_ws;
    float*    phi   = (float*)ws;                         ws += (size_t)NN * HH * 4;
    ushort_t* h     = (ushort_t*)ws;                      ws += (size_t)NN * GG * 2;
    ushort_t* repg  = (ushort_t*)ws;                      ws += (size_t)NN * GG * 2;
    int*      cntI  = (int*)ws;                           ws += (size_t)NN * 4;
    float*    dis   = (float*)ws;                         ws += (size_t)NN * 4;
    float*    inv   = (float*)ws;                         ws += (size_t)NN * 4;
    float*    z     = (float*)ws;                         ws += (size_t)NN * 4;
    int*      start = (int*)ws;                           ws += (size_t)NN * 4;
    int*      cur   = (int*)ws;                           ws += (size_t)NN * 4;
    int2*     cs    = (int2*)ws;                          ws += (size_t)EE * 8;
    int*      flags = (int*)ws;                           ws += 8;
    int*      total = (int*)ws;                           ws += 8;
    unsigned short* Bpk = (unsigned short*)ws;            // 2*NT*KT*64*8 bf16

    hipMemsetAsync(cntI, 0, (size_t)NN * sizeof(int), stream);
    hipMemsetAsync(total, 0, sizeof(int), stream);

    k_probe <<<1,                  256, 0, stream>>>(ei, (const unsigned int*)X, flags);
    k_count <<<(EE + 255) / 256,   256, 0, stream>>>(ei, flags, cntI);
    k_pack  <<<2 * NT * KT,         64, 0, stream>>>(W00, b00, W10, b10, flags, Bpk);
    k_phi   <<<NN / 16,            256, 0, stream>>>(X, Wphi, bphi, flags, phi);
    k_gcn   <<<NN / 16,            256, 0, stream>>>(phi, T, Wgcn, flags, h);
    k_prep  <<<(NN + 255) / 256,   256, 0, stream>>>(cntI, dis, inv);
    k_alloc <<<(NN + 255) / 256,   256, 0, stream>>>(cntI, start, cur, total);
    k_fill  <<<(EE + 255) / 256,   256, 0, stream>>>(ei, flags, dis, cur, cs);
    k_gather<<<NN,                 128, 0, stream>>>(h, cs, start, cntI, T, phi,
                                                     inv, bgcn, flags,
                                                     z, repg, out + 2 * (size_t)NN);
    k_heads_mfma<<<NN / 32,        128, 0, stream>>>(phi, repg, z, Bpk,
                                                     W01, b01, W11, b11, flags, out);
}